// Round 3
// baseline (418.564 us; speedup 1.0000x reference)
//
#include <hip/hip_runtime.h>

#ifndef __has_builtin
#define __has_builtin(x) 0
#endif

#define NOBS_OS 8
#define NOBS_TS 6
#define HID 128
#define NACT 9
#define BTOT 32768
#define NTS 32
#define ROWS 16        // batch rows per tile
#define NTILES 2048    // 2048*16 = 32768
#define MAIN_BLOCKS 1024
#define TILES_PER_BLK 2
#define BLOCK 512      // 8 waves; wave w owns hidden cols [16w,16w+16)

// workspace layout (int32 offsets)
#define HIST_OFF 0
#define OFFS_OFF 64
#define LEN_OFF 128
#define PERM_OFF (128 + BTOT)

typedef __attribute__((ext_vector_type(8))) short short8;
typedef __attribute__((ext_vector_type(4))) float f32x4;

__device__ inline unsigned short f2bf(float x) {
  unsigned int u = __float_as_uint(x);
  u += 0x7FFFu + ((u >> 16) & 1u);
  return (unsigned short)(u >> 16);
}

__device__ inline float fexp2(float x) {
#if __has_builtin(__builtin_amdgcn_exp2f)
  return __builtin_amdgcn_exp2f(x);
#else
  return exp2f(x);
#endif
}
__device__ inline float frcp_(float x) {
#if __has_builtin(__builtin_amdgcn_rcpf)
  return __builtin_amdgcn_rcpf(x);
#else
  return 1.0f / x;
#endif
}
__device__ inline float fsigmoid(float x) {
  return frcp_(1.0f + fexp2(x * -1.44269504088896340736f));
}
__device__ inline float ftanh_(float x) {
  float e = fexp2(x * -2.88539008177792681472f); // exp(-2x)
  return (1.0f - e) * frcp_(1.0f + e);
}

__device__ inline short8 pack8(f32x4 a, f32x4 b) {
  short8 r;
  r[0] = (short)f2bf(a[0]); r[1] = (short)f2bf(a[1]);
  r[2] = (short)f2bf(a[2]); r[3] = (short)f2bf(a[3]);
  r[4] = (short)f2bf(b[0]); r[5] = (short)f2bf(b[1]);
  r[6] = (short)f2bf(b[2]); r[7] = (short)f2bf(b[3]);
  return r;
}

// ---- counting-sort pre-pass --------------------------------------------
__global__ void zero_hist_kernel(int* ws) {
  if (threadIdx.x < 128) ws[threadIdx.x] = 0;
}

__global__ void count_kernel(const float* __restrict__ s, int* __restrict__ ws) {
  const int row = blockIdx.x * blockDim.x + threadIdx.x;
  if (row >= BTOT) return;
  const float* p = s + (size_t)row * 200 + NOBS_OS;
  int n = 0;
#pragma unroll
  for (int t = 0; t < NTS; ++t) {
    const float v = p[t * NOBS_TS];
    n += (v == v) ? 1 : 0;
  }
  ws[LEN_OFF + row] = n;
  atomicAdd(&ws[HIST_OFF + n], 1);
}

__global__ void scan_kernel(int* ws) {
  if (threadIdx.x == 0) {
    int acc = 0;
    for (int i = 0; i <= NTS; ++i) {
      ws[OFFS_OFF + i] = acc;
      acc += ws[HIST_OFF + i];
    }
  }
}

__global__ void scatter_kernel(int* __restrict__ ws) {
  const int row = blockIdx.x * blockDim.x + threadIdx.x;
  if (row >= BTOT) return;
  const int pos = atomicAdd(&ws[OFFS_OFF + ws[LEN_OFF + row]], 1);
  ws[PERM_OFF + pos] = row;
}

// ---- main fused kernel --------------------------------------------------
// A-frag layout in LDS (16 rows x K): elem idx = kt*512 + lane*8 + jj
// C-layout writes at column k: idx = (k>>5)*512 + ((k>>3)&3)*128 + m*8 + (k&7)

__global__ __launch_bounds__(BLOCK, 2) void recdqn_kernel(
    const float* __restrict__ s, const float* __restrict__ W_os,
    const float* __restrict__ b_os, const float* __restrict__ W_ih,
    const float* __restrict__ W_hh, const float* __restrict__ b_ih,
    const float* __restrict__ b_hh, const float* __restrict__ W_ts,
    const float* __restrict__ b_ts, const float* __restrict__ W_c1,
    const float* __restrict__ b_c1, const float* __restrict__ W_c2,
    const float* __restrict__ b_c2, const int* __restrict__ ws,
    float* __restrict__ out) {
  __shared__ unsigned short x_st[ROWS * 264]; // [row][t][8] bf16
  __shared__ unsigned short hA[2][2048];      // h in A-frag layout, double buffered
  __shared__ unsigned short xcat[4096];       // concat(x_OS, x_TS) A-frag (K=256)
  __shared__ unsigned short x2[2048];         // W_c1 output A-frag (K=128)
  __shared__ int n_lds[ROWS];
  __shared__ int rid_s[ROWS];
  __shared__ int tmax_s;

  const int tid = threadIdx.x;
  const int lane = tid & 63;
  const int w = tid >> 6;   // wave 0..7: hidden cols [16w, 16w+16)
  const int c = lane & 15;
  const int q = lane >> 4;
  const int j = (w << 4) | c; // this lane's hidden/output column

  const short8 z8 = {0, 0, 0, 0, 0, 0, 0, 0};

  // ---- one-time: W_hh/W_ih B-fragments (bf16) + combined bias, register-resident.
  short8 Bh[4][5];
  float bias_a[4];
#pragma unroll
  for (int a = 0; a < 4; ++a) {
    const int n = (a << 7) + j;
    bias_a[a] = b_ih[n] + b_hh[n];
#pragma unroll
    for (int kt = 0; kt < 4; ++kt) {
      const f32x4* p = (const f32x4*)(W_hh + n * HID + kt * 32 + q * 8);
      Bh[a][kt] = pack8(p[0], p[1]);
    }
    short8 fx = z8;
    if (q == 0) { // k = 128 + jj : W_ih rows (jj<6), zero-padded
      const float* px = W_ih + n * NOBS_TS;
      fx[0] = (short)f2bf(px[0]); fx[1] = (short)f2bf(px[1]);
      fx[2] = (short)f2bf(px[2]); fx[3] = (short)f2bf(px[3]);
      fx[4] = (short)f2bf(px[4]); fx[5] = (short)f2bf(px[5]);
    }
    Bh[a][4] = fx;
  }

  // C-layout -> A-frag-layout write base for column j, rows m = q*4 + r
  const int pbase = ((j >> 5) << 9) + (((j >> 3) & 3) << 7) + (q << 5) + (j & 7);

  for (int tp = 0; tp < TILES_PER_BLK; ++tp) {
    // pair long and short tiles for load balance
    const int tt = (tp == 0) ? blockIdx.x : (NTILES - 1 - blockIdx.x);
    __syncthreads(); // protect LDS reuse across tiles

    if (tid < ROWS) {
      const int row = ws[PERM_OFF + tt * ROWS + tid];
      rid_s[tid] = row;
      n_lds[tid] = ws[LEN_OFF + row];
    }
    for (int i = tid; i < ROWS * 264; i += BLOCK) x_st[i] = 0;
    __syncthreads();

    // ---- stage s_TS -> LDS bf16 (only valid t; rest stays zero)
    {
      const int r = tid >> 5, t = tid & 31; // 512 threads == ROWS*NTS slots
      if (t < n_lds[r]) {
        const float* src = s + (size_t)rid_s[r] * 200 + NOBS_OS + t * NOBS_TS;
#pragma unroll
        for (int e = 0; e < 6; ++e) x_st[r * 264 + t * 8 + e] = f2bf(src[e]);
      }
    }
    if (tid == 0) {
      int m = 0;
      for (int r = 0; r < ROWS; ++r) m = max(m, n_lds[r]);
      tmax_s = m;
    }
    __syncthreads();
    const int tmax = tmax_s;
    int tcap[4];
#pragma unroll
    for (int r = 0; r < 4; ++r) tcap[r] = n_lds[q * 4 + r] - 1;

    float cc[4], xts[4];
#pragma unroll
    for (int i = 0; i < 4; ++i) { cc[i] = 0.0f; xts[i] = 0.0f; }

    // ---- LSTM time loop (tile rows have ~equal length after sort)
    for (int t = 0; t < tmax; ++t) {
      f32x4 acc[4];
#pragma unroll
      for (int a = 0; a < 4; ++a) {
        const float bb = bias_a[a];
        f32x4 bv = {bb, bb, bb, bb};
        acc[a] = bv;
      }
      // x-gate part (K-tile 4)
      short8 ax = z8;
      if (q == 0) ax = *(const short8*)&x_st[c * 264 + t * 8];
#pragma unroll
      for (int a = 0; a < 4; ++a)
        acc[a] = __builtin_amdgcn_mfma_f32_16x16x32_bf16(ax, Bh[a][4], acc[a], 0, 0, 0);
      // h part (K-tiles 0..3); h == 0 at t == 0
      if (t > 0) {
        const unsigned short* hb = hA[(t + 1) & 1];
#pragma unroll
        for (int kt = 0; kt < 4; ++kt) {
          const short8 ah = *(const short8*)&hb[kt * 512 + lane * 8];
#pragma unroll
          for (int a = 0; a < 4; ++a)
            acc[a] = __builtin_amdgcn_mfma_f32_16x16x32_bf16(ah, Bh[a][kt], acc[a], 0, 0, 0);
        }
      }
      // activations + state update; write new h (bf16) into other buffer
      unsigned short* hw = &hA[t & 1][pbase];
#pragma unroll
      for (int r = 0; r < 4; ++r) {
        const float iv = fsigmoid(acc[0][r]);
        const float fv = fsigmoid(acc[1][r]);
        const float gv = ftanh_(acc[2][r]);
        const float ov = fsigmoid(acc[3][r]);
        const float cv = fv * cc[r] + iv * gv;
        cc[r] = cv;
        const float hv = ov * ftanh_(cv);
        if (t == tcap[r]) xts[r] = hv; // capture f32 h at t == n_obs-1
        hw[r * 8] = f2bf(hv);
      }
      __syncthreads();
    }

    // ---- x_TS raw -> hA[0] in A-frag layout (zeros if n_obs==0)
    {
      unsigned short* pw = &hA[0][pbase];
#pragma unroll
      for (int r = 0; r < 4; ++r) pw[r * 8] = f2bf(xts[r]);
    }
    __syncthreads();

    // ---- x_TS = relu(x_TS @ W_ts^T + b_ts) -> xcat k=128+j
    {
      const float bb = b_ts[j];
      f32x4 acc2 = {bb, bb, bb, bb};
#pragma unroll
      for (int kt = 0; kt < 4; ++kt) {
        const short8 af = *(const short8*)&hA[0][kt * 512 + lane * 8];
        const f32x4* p = (const f32x4*)(W_ts + j * HID + kt * 32 + q * 8);
        acc2 = __builtin_amdgcn_mfma_f32_16x16x32_bf16(af, pack8(p[0], p[1]), acc2, 0, 0, 0);
      }
      unsigned short* pw = &xcat[2048 + pbase];
#pragma unroll
      for (int r = 0; r < 4; ++r) pw[r * 8] = f2bf(fmaxf(acc2[r], 0.0f));
    }

    // ---- x_OS = relu(s_OS @ W_os^T + b_os) -> xcat k=j
    {
      short8 aos = z8;
      if (q == 0) {
        const f32x4* p = (const f32x4*)(s + (size_t)rid_s[c] * 200);
        aos = pack8(p[0], p[1]);
      }
      const float bb = b_os[j];
      f32x4 acc2 = {bb, bb, bb, bb};
      short8 bf = z8;
      if (q == 0) {
        const f32x4* p = (const f32x4*)(W_os + j * NOBS_OS);
        bf = pack8(p[0], p[1]);
      }
      acc2 = __builtin_amdgcn_mfma_f32_16x16x32_bf16(aos, bf, acc2, 0, 0, 0);
      unsigned short* pw = &xcat[pbase];
#pragma unroll
      for (int r = 0; r < 4; ++r) pw[r * 8] = f2bf(fmaxf(acc2[r], 0.0f));
    }
    __syncthreads();

    // ---- x = relu(xcat @ W_c1^T + b_c1) -> x2 (K=256)
    {
      const float bb = b_c1[j];
      f32x4 acc2 = {bb, bb, bb, bb};
#pragma unroll
      for (int kt = 0; kt < 8; ++kt) {
        const short8 af = *(const short8*)&xcat[kt * 512 + lane * 8];
        const f32x4* p = (const f32x4*)(W_c1 + j * 256 + kt * 32 + q * 8);
        acc2 = __builtin_amdgcn_mfma_f32_16x16x32_bf16(af, pack8(p[0], p[1]), acc2, 0, 0, 0);
      }
      unsigned short* pw = &x2[pbase];
#pragma unroll
      for (int r = 0; r < 4; ++r) pw[r * 8] = f2bf(fmaxf(acc2[r], 0.0f));
    }
    __syncthreads();

    // ---- out = x2 @ W_c2^T + b_c2 (wave 0 only; cols c<9 valid)
    if (w == 0) {
      const float bb = (c < NACT) ? b_c2[c] : 0.0f;
      f32x4 accf = {bb, bb, bb, bb};
#pragma unroll
      for (int kt = 0; kt < 4; ++kt) {
        const short8 af = *(const short8*)&x2[kt * 512 + lane * 8];
        short8 bf = z8;
        if (c < NACT) {
          const f32x4* p = (const f32x4*)(W_c2 + c * HID + kt * 32 + q * 8);
          bf = pack8(p[0], p[1]);
        }
        accf = __builtin_amdgcn_mfma_f32_16x16x32_bf16(af, bf, accf, 0, 0, 0);
      }
      if (c < NACT) {
#pragma unroll
        for (int r = 0; r < 4; ++r)
          out[(size_t)rid_s[q * 4 + r] * NACT + c] = accf[r];
      }
    }
  }
}

extern "C" void kernel_launch(void* const* d_in, const int* in_sizes, int n_in,
                              void* d_out, int out_size, void* d_ws, size_t ws_size,
                              hipStream_t stream) {
  (void)in_sizes; (void)n_in; (void)out_size; (void)ws_size;
  const float* s    = (const float*)d_in[0];
  const float* W_os = (const float*)d_in[1];
  const float* b_os = (const float*)d_in[2];
  const float* W_ih = (const float*)d_in[3];
  const float* W_hh = (const float*)d_in[4];
  const float* b_ih = (const float*)d_in[5];
  const float* b_hh = (const float*)d_in[6];
  const float* W_ts = (const float*)d_in[7];
  const float* b_ts = (const float*)d_in[8];
  const float* W_c1 = (const float*)d_in[9];
  const float* b_c1 = (const float*)d_in[10];
  const float* W_c2 = (const float*)d_in[11];
  const float* b_c2 = (const float*)d_in[12];
  int* ws = (int*)d_ws;
  float* outp = (float*)d_out;

  zero_hist_kernel<<<1, 128, 0, stream>>>(ws);
  count_kernel<<<BTOT / 256, 256, 0, stream>>>(s, ws);
  scan_kernel<<<1, 64, 0, stream>>>(ws);
  scatter_kernel<<<BTOT / 256, 256, 0, stream>>>(ws);
  recdqn_kernel<<<MAIN_BLOCKS, BLOCK, 0, stream>>>(
      s, W_os, b_os, W_ih, W_hh, b_ih, b_hh, W_ts, b_ts, W_c1, b_c1, W_c2,
      b_c2, ws, outp);
}

// Round 4
// 296.955 us; speedup vs baseline: 1.4095x; 1.4095x over previous
//
#include <hip/hip_runtime.h>

#ifndef __has_builtin
#define __has_builtin(x) 0
#endif

#define NOBS_OS 8
#define NOBS_TS 6
#define HID 128
#define NACT 9
#define BTOT 32768
#define NTS 32
#define ROWS 16        // batch rows per tile
#define NTILES 2048    // 2048*16 = 32768
#define MAIN_BLOCKS 1024
#define TILES_PER_BLK 2
#define BLOCK 512      // 8 waves; wave w owns hidden cols [16w,16w+16)

// workspace layout (int32 offsets)
#define HIST_OFF 0
#define OFFS_OFF 64
#define LEN_OFF 128
#define PERM_OFF (128 + BTOT)

typedef __attribute__((ext_vector_type(8))) short short8;
typedef __attribute__((ext_vector_type(4))) float f32x4;

__device__ inline unsigned short f2bf(float x) {
  unsigned int u = __float_as_uint(x);
  u += 0x7FFFu + ((u >> 16) & 1u);
  return (unsigned short)(u >> 16);
}

__device__ inline float fexp2(float x) {
#if __has_builtin(__builtin_amdgcn_exp2f)
  return __builtin_amdgcn_exp2f(x);
#else
  return exp2f(x);
#endif
}
__device__ inline float frcp_(float x) {
#if __has_builtin(__builtin_amdgcn_rcpf)
  return __builtin_amdgcn_rcpf(x);
#else
  return 1.0f / x;
#endif
}
__device__ inline float fsigmoid(float x) {
  return frcp_(1.0f + fexp2(x * -1.44269504088896340736f));
}
__device__ inline float ftanh_(float x) {
  float e = fexp2(x * -2.88539008177792681472f); // exp(-2x)
  return (1.0f - e) * frcp_(1.0f + e);
}

__device__ inline short8 pack8(f32x4 a, f32x4 b) {
  short8 r;
  r[0] = (short)f2bf(a[0]); r[1] = (short)f2bf(a[1]);
  r[2] = (short)f2bf(a[2]); r[3] = (short)f2bf(a[3]);
  r[4] = (short)f2bf(b[0]); r[5] = (short)f2bf(b[1]);
  r[6] = (short)f2bf(b[2]); r[7] = (short)f2bf(b[3]);
  return r;
}

// ---- counting-sort pre-pass (LDS-aggregated) ----------------------------
__global__ void zero_hist_kernel(int* ws) {
  if (threadIdx.x < 128) ws[threadIdx.x] = 0;
}

// lengths via binary search on the NaN valid-prefix; per-block LDS histogram
__global__ void count_kernel(const float* __restrict__ s, int* __restrict__ ws) {
  __shared__ int lh[NTS + 1];
  const int tid = threadIdx.x;
  if (tid <= NTS) lh[tid] = 0;
  __syncthreads();
  const int row = blockIdx.x * 256 + tid;
  const float* p = s + (size_t)row * 200 + NOBS_OS;
  int lo = 0, hi = NTS;
  while (lo < hi) {
    const int mid = (lo + hi) >> 1;
    const float v = p[mid * NOBS_TS];
    if (v == v) lo = mid + 1; else hi = mid;
  }
  ws[LEN_OFF + row] = lo;
  atomicAdd(&lh[lo], 1);
  __syncthreads();
  if (tid <= NTS && lh[tid]) atomicAdd(&ws[HIST_OFF + tid], lh[tid]);
}

__global__ void scan_kernel(int* ws) {
  if (threadIdx.x == 0) {
    int acc = 0;
    for (int i = 0; i <= NTS; ++i) {
      ws[OFFS_OFF + i] = acc;
      acc += ws[HIST_OFF + i];
    }
  }
}

// per-block chunk reservation per bin; intra-block rank via LDS atomics
__global__ void scatter_kernel(int* __restrict__ ws) {
  __shared__ int lh[NTS + 1];
  __shared__ int lbase[NTS + 1];
  const int tid = threadIdx.x;
  if (tid <= NTS) lh[tid] = 0;
  __syncthreads();
  const int row = blockIdx.x * 256 + tid;
  const int len = ws[LEN_OFF + row];
  const int lrank = atomicAdd(&lh[len], 1);
  __syncthreads();
  if (tid <= NTS && lh[tid]) lbase[tid] = atomicAdd(&ws[OFFS_OFF + tid], lh[tid]);
  __syncthreads();
  ws[PERM_OFF + lbase[len] + lrank] = row;
}

// ---- main fused kernel --------------------------------------------------
// A-frag layout in LDS (16 rows x K): elem idx = kt*512 + lane*8 + jj
// C-layout writes at column k: idx = (k>>5)*512 + ((k>>3)&3)*128 + m*8 + (k&7)

__global__ __launch_bounds__(BLOCK, 2) void recdqn_kernel(
    const float* __restrict__ s, const float* __restrict__ W_os,
    const float* __restrict__ b_os, const float* __restrict__ W_ih,
    const float* __restrict__ W_hh, const float* __restrict__ b_ih,
    const float* __restrict__ b_hh, const float* __restrict__ W_ts,
    const float* __restrict__ b_ts, const float* __restrict__ W_c1,
    const float* __restrict__ b_c1, const float* __restrict__ W_c2,
    const float* __restrict__ b_c2, const int* __restrict__ ws,
    float* __restrict__ out) {
  __shared__ unsigned short x_st[ROWS * 264]; // [row][t][8] bf16
  __shared__ unsigned short hA[2][2048];      // h in A-frag layout, double buffered
  __shared__ unsigned short xcat[4096];       // concat(x_OS, x_TS) A-frag (K=256)
  __shared__ unsigned short x2[2048];         // W_c1 output A-frag (K=128)
  __shared__ int n_lds[ROWS];
  __shared__ int rid_s[ROWS];
  __shared__ int tmax_s;

  const int tid = threadIdx.x;
  const int lane = tid & 63;
  const int w = tid >> 6;   // wave 0..7: hidden cols [16w, 16w+16)
  const int c = lane & 15;
  const int q = lane >> 4;
  const int j = (w << 4) | c; // this lane's hidden/output column

  const short8 z8 = {0, 0, 0, 0, 0, 0, 0, 0};

  // ---- one-time: W_hh/W_ih B-fragments (bf16) + combined bias, register-resident.
  short8 Bh[4][5];
  float bias_a[4];
#pragma unroll
  for (int a = 0; a < 4; ++a) {
    const int n = (a << 7) + j;
    bias_a[a] = b_ih[n] + b_hh[n];
#pragma unroll
    for (int kt = 0; kt < 4; ++kt) {
      const f32x4* p = (const f32x4*)(W_hh + n * HID + kt * 32 + q * 8);
      Bh[a][kt] = pack8(p[0], p[1]);
    }
    short8 fx = z8;
    if (q == 0) { // k = 128 + jj : W_ih rows (jj<6), zero-padded
      const float* px = W_ih + n * NOBS_TS;
      fx[0] = (short)f2bf(px[0]); fx[1] = (short)f2bf(px[1]);
      fx[2] = (short)f2bf(px[2]); fx[3] = (short)f2bf(px[3]);
      fx[4] = (short)f2bf(px[4]); fx[5] = (short)f2bf(px[5]);
    }
    Bh[a][4] = fx;
  }

  // C-layout -> A-frag-layout write base for column j, rows m = q*4 + r
  const int pbase = ((j >> 5) << 9) + (((j >> 3) & 3) << 7) + (q << 5) + (j & 7);

  for (int tp = 0; tp < TILES_PER_BLK; ++tp) {
    // pair long and short tiles for load balance
    const int tt = (tp == 0) ? blockIdx.x : (NTILES - 1 - blockIdx.x);
    __syncthreads(); // protect LDS reuse across tiles

    if (tid < ROWS) {
      const int row = ws[PERM_OFF + tt * ROWS + tid];
      rid_s[tid] = row;
      n_lds[tid] = ws[LEN_OFF + row];
    }
    for (int i = tid; i < ROWS * 264; i += BLOCK) x_st[i] = 0;
    __syncthreads();

    // ---- stage s_TS -> LDS bf16 (only valid t; rest stays zero)
    {
      const int r = tid >> 5, t = tid & 31; // 512 threads == ROWS*NTS slots
      if (t < n_lds[r]) {
        const float* src = s + (size_t)rid_s[r] * 200 + NOBS_OS + t * NOBS_TS;
#pragma unroll
        for (int e = 0; e < 6; ++e) x_st[r * 264 + t * 8 + e] = f2bf(src[e]);
      }
    }
    if (tid == 0) {
      int m = 0;
      for (int r = 0; r < ROWS; ++r) m = max(m, n_lds[r]);
      tmax_s = m;
    }
    __syncthreads();
    const int tmax = tmax_s;
    int tcap[4];
#pragma unroll
    for (int r = 0; r < 4; ++r) tcap[r] = n_lds[q * 4 + r] - 1;

    float cc[4], xts[4];
#pragma unroll
    for (int i = 0; i < 4; ++i) { cc[i] = 0.0f; xts[i] = 0.0f; }

    // ---- LSTM time loop (tile rows have ~equal length after sort)
    for (int t = 0; t < tmax; ++t) {
      f32x4 acc[4];
#pragma unroll
      for (int a = 0; a < 4; ++a) {
        const float bb = bias_a[a];
        f32x4 bv = {bb, bb, bb, bb};
        acc[a] = bv;
      }
      // x-gate part (K-tile 4)
      short8 ax = z8;
      if (q == 0) ax = *(const short8*)&x_st[c * 264 + t * 8];
#pragma unroll
      for (int a = 0; a < 4; ++a)
        acc[a] = __builtin_amdgcn_mfma_f32_16x16x32_bf16(ax, Bh[a][4], acc[a], 0, 0, 0);
      // h part (K-tiles 0..3); h == 0 at t == 0
      if (t > 0) {
        const unsigned short* hb = hA[(t + 1) & 1];
#pragma unroll
        for (int kt = 0; kt < 4; ++kt) {
          const short8 ah = *(const short8*)&hb[kt * 512 + lane * 8];
#pragma unroll
          for (int a = 0; a < 4; ++a)
            acc[a] = __builtin_amdgcn_mfma_f32_16x16x32_bf16(ah, Bh[a][kt], acc[a], 0, 0, 0);
        }
      }
      // activations + state update; write new h (bf16) into other buffer
      unsigned short* hw = &hA[t & 1][pbase];
#pragma unroll
      for (int r = 0; r < 4; ++r) {
        const float iv = fsigmoid(acc[0][r]);
        const float fv = fsigmoid(acc[1][r]);
        const float gv = ftanh_(acc[2][r]);
        const float ov = fsigmoid(acc[3][r]);
        const float cv = fv * cc[r] + iv * gv;
        cc[r] = cv;
        const float hv = ov * ftanh_(cv);
        if (t == tcap[r]) xts[r] = hv; // capture f32 h at t == n_obs-1
        hw[r * 8] = f2bf(hv);
      }
      __syncthreads();
    }

    // ---- x_TS raw -> hA[0] in A-frag layout (zeros if n_obs==0)
    {
      unsigned short* pw = &hA[0][pbase];
#pragma unroll
      for (int r = 0; r < 4; ++r) pw[r * 8] = f2bf(xts[r]);
    }
    __syncthreads();

    // ---- x_TS = relu(x_TS @ W_ts^T + b_ts) -> xcat k=128+j
    {
      const float bb = b_ts[j];
      f32x4 acc2 = {bb, bb, bb, bb};
#pragma unroll
      for (int kt = 0; kt < 4; ++kt) {
        const short8 af = *(const short8*)&hA[0][kt * 512 + lane * 8];
        const f32x4* p = (const f32x4*)(W_ts + j * HID + kt * 32 + q * 8);
        acc2 = __builtin_amdgcn_mfma_f32_16x16x32_bf16(af, pack8(p[0], p[1]), acc2, 0, 0, 0);
      }
      unsigned short* pw = &xcat[2048 + pbase];
#pragma unroll
      for (int r = 0; r < 4; ++r) pw[r * 8] = f2bf(fmaxf(acc2[r], 0.0f));
    }

    // ---- x_OS = relu(s_OS @ W_os^T + b_os) -> xcat k=j
    {
      short8 aos = z8;
      if (q == 0) {
        const f32x4* p = (const f32x4*)(s + (size_t)rid_s[c] * 200);
        aos = pack8(p[0], p[1]);
      }
      const float bb = b_os[j];
      f32x4 acc2 = {bb, bb, bb, bb};
      short8 bf = z8;
      if (q == 0) {
        const f32x4* p = (const f32x4*)(W_os + j * NOBS_OS);
        bf = pack8(p[0], p[1]);
      }
      acc2 = __builtin_amdgcn_mfma_f32_16x16x32_bf16(aos, bf, acc2, 0, 0, 0);
      unsigned short* pw = &xcat[pbase];
#pragma unroll
      for (int r = 0; r < 4; ++r) pw[r * 8] = f2bf(fmaxf(acc2[r], 0.0f));
    }
    __syncthreads();

    // ---- x = relu(xcat @ W_c1^T + b_c1) -> x2 (K=256)
    {
      const float bb = b_c1[j];
      f32x4 acc2 = {bb, bb, bb, bb};
#pragma unroll
      for (int kt = 0; kt < 8; ++kt) {
        const short8 af = *(const short8*)&xcat[kt * 512 + lane * 8];
        const f32x4* p = (const f32x4*)(W_c1 + j * 256 + kt * 32 + q * 8);
        acc2 = __builtin_amdgcn_mfma_f32_16x16x32_bf16(af, pack8(p[0], p[1]), acc2, 0, 0, 0);
      }
      unsigned short* pw = &x2[pbase];
#pragma unroll
      for (int r = 0; r < 4; ++r) pw[r * 8] = f2bf(fmaxf(acc2[r], 0.0f));
    }
    __syncthreads();

    // ---- out = x2 @ W_c2^T + b_c2 (wave 0 only; cols c<9 valid)
    if (w == 0) {
      const float bb = (c < NACT) ? b_c2[c] : 0.0f;
      f32x4 accf = {bb, bb, bb, bb};
#pragma unroll
      for (int kt = 0; kt < 4; ++kt) {
        const short8 af = *(const short8*)&x2[kt * 512 + lane * 8];
        short8 bf = z8;
        if (c < NACT) {
          const f32x4* p = (const f32x4*)(W_c2 + c * HID + kt * 32 + q * 8);
          bf = pack8(p[0], p[1]);
        }
        accf = __builtin_amdgcn_mfma_f32_16x16x32_bf16(af, bf, accf, 0, 0, 0);
      }
      if (c < NACT) {
#pragma unroll
        for (int r = 0; r < 4; ++r)
          out[(size_t)rid_s[q * 4 + r] * NACT + c] = accf[r];
      }
    }
  }
}

extern "C" void kernel_launch(void* const* d_in, const int* in_sizes, int n_in,
                              void* d_out, int out_size, void* d_ws, size_t ws_size,
                              hipStream_t stream) {
  (void)in_sizes; (void)n_in; (void)out_size; (void)ws_size;
  const float* s    = (const float*)d_in[0];
  const float* W_os = (const float*)d_in[1];
  const float* b_os = (const float*)d_in[2];
  const float* W_ih = (const float*)d_in[3];
  const float* W_hh = (const float*)d_in[4];
  const float* b_ih = (const float*)d_in[5];
  const float* b_hh = (const float*)d_in[6];
  const float* W_ts = (const float*)d_in[7];
  const float* b_ts = (const float*)d_in[8];
  const float* W_c1 = (const float*)d_in[9];
  const float* b_c1 = (const float*)d_in[10];
  const float* W_c2 = (const float*)d_in[11];
  const float* b_c2 = (const float*)d_in[12];
  int* ws = (int*)d_ws;
  float* outp = (float*)d_out;

  zero_hist_kernel<<<1, 128, 0, stream>>>(ws);
  count_kernel<<<BTOT / 256, 256, 0, stream>>>(s, ws);
  scan_kernel<<<1, 64, 0, stream>>>(ws);
  scatter_kernel<<<BTOT / 256, 256, 0, stream>>>(ws);
  recdqn_kernel<<<MAIN_BLOCKS, BLOCK, 0, stream>>>(
      s, W_os, b_os, W_ih, W_hh, b_ih, b_hh, W_ts, b_ts, W_c1, b_c1, W_c2,
      b_c2, ws, outp);
}